// Round 1
// baseline (2474.676 us; speedup 1.0000x reference)
//
#include <hip/hip_runtime.h>
#include <math.h>

constexpr float INV_R   = 0.2f;                     // 1/R_MAX
constexpr float PI_F    = 3.14159265358979323846f;
constexpr float C0      = 0.632455532033675866f;    // sqrt(2/R_MAX)
constexpr float INV_AVG = 1.0f / 16.0f;             // 1/AVG_NEIGH

__device__ __forceinline__ float sigm(float x) { return 1.0f / (1.0f + __expf(-x)); }

// ef[n] = sqrt(2/R) * sin((n+1)*pi*u) / L * fc(u),  via Chebyshev recurrence
__device__ __forceinline__ void radial_ef(float u, float invL, float* ef) {
    float u2 = u * u, u4 = u2 * u2, u5 = u4 * u;
    float fc = 1.f - 21.f * u5 + 35.f * u5 * u - 15.f * u5 * u2;
    float sp, cp;
    sincosf(PI_F * u, &sp, &cp);
    float pref = C0 * invL * fc;
    float twoc = 2.f * cp;
    float s_nm1 = 0.f, s_n = sp;
    ef[0] = pref * s_n;
#pragma unroll
    for (int n = 2; n <= 8; n++) {
        float s_np = twoc * s_n - s_nm1;
        s_nm1 = s_n; s_n = s_np;
        ef[n - 1] = pref * s_n;
    }
}

// ef plus d(ef)/dL
__device__ __forceinline__ void radial_ef_d(float u, float invL, float* ef, float* dd) {
    float u2 = u * u, u4 = u2 * u2, u5 = u4 * u;
    float fc  = 1.f - 21.f * u5 + 35.f * u5 * u - 15.f * u5 * u2;
    float om  = 1.f - u;
    float fcp = -105.f * u4 * om * om;   // dfc/du
    float sp, cp;
    sincosf(PI_F * u, &sp, &cp);
    float twoc = 2.f * cp;
    float a = C0 * invL;
    float s_nm1 = 0.f, s_n = sp, c_nm1 = 1.f, c_n = cp;
#pragma unroll
    for (int n = 1; n <= 8; n++) {
        ef[n - 1] = a * s_n * fc;
        dd[n - 1] = a * fc * ((float)n * PI_F * INV_R * c_n - s_n * invL)
                  + a * s_n * fcp * INV_R;
        if (n < 8) {
            float sn2 = twoc * s_n - s_nm1; s_nm1 = s_n; s_n = sn2;
            float cn2 = twoc * c_n - c_nm1; c_nm1 = c_n; c_n = cn2;
        }
    }
}

__global__ __launch_bounds__(256) void k_embed(
    const float* __restrict__ attrs, const float* __restrict__ ae,
    const float* __restrict__ Wemb, float* __restrict__ h,
    float* __restrict__ e0, int N)
{
    int i = blockIdx.x * blockDim.x + threadIdx.x;
    if (i >= N) return;
    float a[10];
#pragma unroll
    for (int k = 0; k < 10; k++) a[k] = attrs[i * 10 + k];
    float e = 0.f;
#pragma unroll
    for (int k = 0; k < 10; k++) e += a[k] * ae[k];
    e0[i] = e;
#pragma unroll
    for (int c = 0; c < 32; c++) {
        float v = 0.f;
#pragma unroll
        for (int k = 0; k < 10; k++) v += a[k] * Wemb[k * 32 + c];
        h[i * 32 + c] = v;
    }
}

// Unified edge kernel: tw = silu(ef@W1)@W2[:, :32];
// acc[scatter_node] += feat[gather_node] * tw   (atomic)
// swapdir=0: gather=sender, scatter=receiver (forward message passing)
// swapdir=1: gather=receiver, scatter=sender  (backward g1 scatter)
__global__ __launch_bounds__(256) void k_edge_mlp(
    const float* __restrict__ pos, const float* __restrict__ shifts,
    const int* __restrict__ ei, const float* __restrict__ W1,
    const float* __restrict__ W2, const float* __restrict__ feat,
    float* __restrict__ acc, int E, int swapdir)
{
    int e = blockIdx.x * blockDim.x + threadIdx.x;
    if (e >= E) return;
    int s = ei[e], r = ei[E + e];
    float vx = pos[3 * r + 0] - pos[3 * s + 0] + shifts[3 * e + 0];
    float vy = pos[3 * r + 1] - pos[3 * s + 1] + shifts[3 * e + 1];
    float vz = pos[3 * r + 2] - pos[3 * s + 2] + shifts[3 * e + 2];
    float ss2 = vx * vx + vy * vy + vz * vz;
    float L = sqrtf(fmaxf(ss2, 1e-12f));
    float u = L * INV_R;
    if (u >= 1.f) return;   // fc=0 -> ef=0 -> silu(0)=0 -> zero contribution
    float invL = 1.f / L;
    float ef[8];
    radial_ef(u, invL, ef);

    float tw[32];
#pragma unroll
    for (int c = 0; c < 32; c++) tw[c] = 0.f;
    for (int j = 0; j < 64; j++) {
        float s1 = 0.f;
#pragma unroll
        for (int k = 0; k < 8; k++) s1 += ef[k] * W1[k * 64 + j];
        float act = s1 * sigm(s1);
        const float* w2 = W2 + j * 96;
#pragma unroll
        for (int c = 0; c < 32; c++) tw[c] += act * w2[c];
    }

    int gn = swapdir ? r : s;
    int sn = swapdir ? s : r;
    const float* fs = feat + (size_t)gn * 32;
    float* dst = acc + (size_t)sn * 32;
#pragma unroll
    for (int c = 0; c < 32; c++) unsafeAtomicAdd(&dst[c], fs[c] * tw[c]);
}

__global__ __launch_bounds__(256) void k_node1(
    const float* __restrict__ h, float* __restrict__ A1,
    const float* __restrict__ Wr1, float* __restrict__ e1, int N)
{
    int i = blockIdx.x * blockDim.x + threadIdx.x;
    if (i >= N) return;
    float dot = 0.f;
#pragma unroll
    for (int c = 0; c < 32; c++) {
        float v = A1[i * 32 + c] * INV_AVG + h[i * 32 + c];
        A1[i * 32 + c] = v;
        dot += v * Wr1[c];
    }
    e1[i] = dot;
}

__global__ __launch_bounds__(256) void k_node2(
    const float* __restrict__ A2acc, const float* __restrict__ A1,
    const float* __restrict__ Wm1, const float* __restrict__ Wm2,
    const float* __restrict__ e0, const float* __restrict__ e1,
    float* __restrict__ g2, float* __restrict__ node_e,
    float* __restrict__ total, const int* __restrict__ batch, int N)
{
    __shared__ float bins[32];
    if (threadIdx.x < 32) bins[threadIdx.x] = 0.f;
    __syncthreads();
    int i = blockIdx.x * blockDim.x + threadIdx.x;
    if (i < N) {
        float A2[32];
#pragma unroll
        for (int c = 0; c < 32; c++)
            A2[c] = A2acc[i * 32 + c] * INV_AVG + A1[i * 32 + c];
        float z[16];
#pragma unroll
        for (int k = 0; k < 16; k++) {
            float v = 0.f;
#pragma unroll
            for (int c = 0; c < 32; c++) v += A2[c] * Wm1[c * 16 + k];
            z[k] = v;
        }
        float e2 = 0.f;
        float wk[16];
#pragma unroll
        for (int k = 0; k < 16; k++) {
            float sg = sigm(z[k]);
            float m2 = Wm2[k];
            e2 += z[k] * sg * m2;
            wk[k] = m2 * sg * (1.f + z[k] * (1.f - sg));  // Wm2 * silu'(z)
        }
#pragma unroll
        for (int c = 0; c < 32; c++) {
            float v = 0.f;
#pragma unroll
            for (int k = 0; k < 16; k++) v += Wm1[c * 16 + k] * wk[k];
            g2[i * 32 + c] = v;
        }
        float ne = e0[i] + e1[i] + e2;
        node_e[i] = ne;
        atomicAdd(&bins[batch[i]], ne);
    }
    __syncthreads();
    if (threadIdx.x < 32) unsafeAtomicAdd(&total[threadIdx.x], bins[threadIdx.x]);
}

__global__ __launch_bounds__(256) void k_node3(
    float* __restrict__ g1, const float* __restrict__ g2,
    const float* __restrict__ Wr1, int N)
{
    int i = blockIdx.x * blockDim.x + threadIdx.x;
    if (i >= N) return;
#pragma unroll
    for (int c = 0; c < 32; c++)
        g1[i * 32 + c] = g1[i * 32 + c] * INV_AVG + g2[i * 32 + c] + Wr1[c];
}

__global__ __launch_bounds__(256) void k_edge_force(
    const float* __restrict__ pos, const float* __restrict__ shifts,
    const int* __restrict__ ei,
    const float* __restrict__ W1a, const float* __restrict__ W2a,
    const float* __restrict__ W1b, const float* __restrict__ W2b,
    const float* __restrict__ h, const float* __restrict__ A1,
    const float* __restrict__ g1, const float* __restrict__ g2,
    float* __restrict__ forces, int E)
{
    int e = blockIdx.x * blockDim.x + threadIdx.x;
    if (e >= E) return;
    int s = ei[e], r = ei[E + e];
    float vx = pos[3 * r + 0] - pos[3 * s + 0] + shifts[3 * e + 0];
    float vy = pos[3 * r + 1] - pos[3 * s + 1] + shifts[3 * e + 1];
    float vz = pos[3 * r + 2] - pos[3 * s + 2] + shifts[3 * e + 2];
    float ss2 = vx * vx + vy * vy + vz * vz;
    if (ss2 <= 1e-12f) return;           // grad of maximum() is 0 -> zero force
    float L = sqrtf(ss2);
    float u = L * INV_R;
    if (u >= 1.f) return;                // d(ef)/dL = 0 beyond cutoff
    float invL = 1.f / L;

    float ef[8], dd[8], def[8];
    radial_ef_d(u, invL, ef, dd);
#pragma unroll
    for (int k = 0; k < 8; k++) def[k] = 0.f;

    // branch a: dtw1 = (1/16) * g1[recv] * h[send]
    {
        float dtw[32];
        const float* gr = g1 + (size_t)r * 32;
        const float* fs = h + (size_t)s * 32;
#pragma unroll
        for (int c = 0; c < 32; c++) dtw[c] = INV_AVG * gr[c] * fs[c];
        for (int j = 0; j < 64; j++) {
            float s1 = 0.f;
#pragma unroll
            for (int k = 0; k < 8; k++) s1 += ef[k] * W1a[k * 64 + j];
            float da = 0.f;
            const float* w2 = W2a + j * 96;
#pragma unroll
            for (int c = 0; c < 32; c++) da += w2[c] * dtw[c];
            float sg = sigm(s1);
            float ds = sg * (1.f + s1 * (1.f - sg)) * da;   // silu'(s1) * da
#pragma unroll
            for (int k = 0; k < 8; k++) def[k] += W1a[k * 64 + j] * ds;
        }
    }
    // branch b: dtw2 = (1/16) * g2[recv] * A1[send]
    {
        float dtw[32];
        const float* gr = g2 + (size_t)r * 32;
        const float* fs = A1 + (size_t)s * 32;
#pragma unroll
        for (int c = 0; c < 32; c++) dtw[c] = INV_AVG * gr[c] * fs[c];
        for (int j = 0; j < 64; j++) {
            float s1 = 0.f;
#pragma unroll
            for (int k = 0; k < 8; k++) s1 += ef[k] * W1b[k * 64 + j];
            float da = 0.f;
            const float* w2 = W2b + j * 96;
#pragma unroll
            for (int c = 0; c < 32; c++) da += w2[c] * dtw[c];
            float sg = sigm(s1);
            float ds = sg * (1.f + s1 * (1.f - sg)) * da;
#pragma unroll
            for (int k = 0; k < 8; k++) def[k] += W1b[k * 64 + j] * ds;
        }
    }

    float dL = 0.f;
#pragma unroll
    for (int k = 0; k < 8; k++) dL += def[k] * dd[k];

    // dE/dpos[r] = dL * vec/L ; forces = -grad
    float sc = -dL * invL;
    float fx = sc * vx, fy = sc * vy, fz = sc * vz;
    unsafeAtomicAdd(&forces[3 * r + 0], fx);
    unsafeAtomicAdd(&forces[3 * r + 1], fy);
    unsafeAtomicAdd(&forces[3 * r + 2], fz);
    unsafeAtomicAdd(&forces[3 * s + 0], -fx);
    unsafeAtomicAdd(&forces[3 * s + 1], -fy);
    unsafeAtomicAdd(&forces[3 * s + 2], -fz);
}

extern "C" void kernel_launch(void* const* d_in, const int* in_sizes, int n_in,
                              void* d_out, int out_size, void* d_ws, size_t ws_size,
                              hipStream_t stream)
{
    const float* pos    = (const float*)d_in[0];
    const float* attrs  = (const float*)d_in[1];
    const float* shifts = (const float*)d_in[2];
    const float* ae     = (const float*)d_in[3];
    const float* Wemb   = (const float*)d_in[4];
    const float* W1a    = (const float*)d_in[5];
    const float* W2a    = (const float*)d_in[6];
    const float* Wr1    = (const float*)d_in[7];
    const float* W1b    = (const float*)d_in[8];
    const float* W2b    = (const float*)d_in[9];
    const float* Wm1    = (const float*)d_in[10];
    const float* Wm2    = (const float*)d_in[11];
    const int*   ei     = (const int*)d_in[12];
    const int*   batch  = (const int*)d_in[13];

    int N = in_sizes[13];
    int E = in_sizes[12] / 2;

    float* out    = (float*)d_out;
    float* total  = out;                 // 32
    float* node_e = out + 32;            // N
    float* forces = out + 32 + N;        // 3N

    float* ws = (float*)d_ws;
    size_t NC = (size_t)N * 32;
    float* h  = ws;            // N*32
    float* A1 = h  + NC;       // N*32 : acc then A1_0 in place
    float* A2 = A1 + NC;       // N*32 : acc
    float* g2 = A2 + NC;       // N*32
    float* g1 = g2 + NC;       // N*32 : acc then final in place
    float* e0 = g1 + NC;       // N
    float* e1 = e0 + N;        // N

    hipMemsetAsync(A1, 0, NC * sizeof(float), stream);
    hipMemsetAsync(A2, 0, NC * sizeof(float), stream);
    hipMemsetAsync(g1, 0, NC * sizeof(float), stream);
    hipMemsetAsync(total, 0, 32 * sizeof(float), stream);
    hipMemsetAsync(forces, 0, (size_t)N * 3 * sizeof(float), stream);

    int nb_n = (N + 255) / 256;
    int nb_e = (E + 255) / 256;

    k_embed<<<nb_n, 256, 0, stream>>>(attrs, ae, Wemb, h, e0, N);
    k_edge_mlp<<<nb_e, 256, 0, stream>>>(pos, shifts, ei, W1a, W2a, h, A1, E, 0);
    k_node1<<<nb_n, 256, 0, stream>>>(h, A1, Wr1, e1, N);
    k_edge_mlp<<<nb_e, 256, 0, stream>>>(pos, shifts, ei, W1b, W2b, A1, A2, E, 0);
    k_node2<<<nb_n, 256, 0, stream>>>(A2, A1, Wm1, Wm2, e0, e1, g2, node_e, total, batch, N);
    k_edge_mlp<<<nb_e, 256, 0, stream>>>(pos, shifts, ei, W1b, W2b, g2, g1, E, 1);
    k_node3<<<nb_n, 256, 0, stream>>>(g1, g2, Wr1, N);
    k_edge_force<<<nb_e, 256, 0, stream>>>(pos, shifts, ei, W1a, W2a, W1b, W2b,
                                           h, A1, g1, g2, forces, E);
}

// Round 2
// 586.395 us; speedup vs baseline: 4.2202x; 4.2202x over previous
//
#include <hip/hip_runtime.h>
#include <math.h>

constexpr float INV_R   = 0.2f;                     // 1/R_MAX
constexpr float PI_F    = 3.14159265358979323846f;
constexpr float C0      = 0.632455532033675866f;    // sqrt(2/R_MAX)
constexpr float INV_AVG = 1.0f / 16.0f;             // 1/AVG_NEIGH

__device__ __forceinline__ float sigm(float x) { return 1.0f / (1.0f + __expf(-x)); }

// ef[n] = sqrt(2/R) * sin((n+1)*pi*u) / L * fc(u),  via Chebyshev recurrence
__device__ __forceinline__ void radial_ef(float u, float invL, float* ef) {
    float u2 = u * u, u4 = u2 * u2, u5 = u4 * u;
    float fc = 1.f - 21.f * u5 + 35.f * u5 * u - 15.f * u5 * u2;
    float sp, cp;
    sincosf(PI_F * u, &sp, &cp);
    float pref = C0 * invL * fc;
    float twoc = 2.f * cp;
    float s_nm1 = 0.f, s_n = sp;
    ef[0] = pref * s_n;
#pragma unroll
    for (int n = 2; n <= 8; n++) {
        float s_np = twoc * s_n - s_nm1;
        s_nm1 = s_n; s_n = s_np;
        ef[n - 1] = pref * s_n;
    }
}

// ef plus d(ef)/dL
__device__ __forceinline__ void radial_ef_d(float u, float invL, float* ef, float* dd) {
    float u2 = u * u, u4 = u2 * u2, u5 = u4 * u;
    float fc  = 1.f - 21.f * u5 + 35.f * u5 * u - 15.f * u5 * u2;
    float om  = 1.f - u;
    float fcp = -105.f * u4 * om * om;   // dfc/du
    float sp, cp;
    sincosf(PI_F * u, &sp, &cp);
    float twoc = 2.f * cp;
    float a = C0 * invL;
    float s_nm1 = 0.f, s_n = sp, c_nm1 = 1.f, c_n = cp;
#pragma unroll
    for (int n = 1; n <= 8; n++) {
        ef[n - 1] = a * s_n * fc;
        dd[n - 1] = a * fc * ((float)n * PI_F * INV_R * c_n - s_n * invL)
                  + a * s_n * fcp * INV_R;
        if (n < 8) {
            float sn2 = twoc * s_n - s_nm1; s_nm1 = s_n; s_n = sn2;
            float cn2 = twoc * c_n - c_nm1; c_nm1 = c_n; c_n = cn2;
        }
    }
}

__global__ __launch_bounds__(256) void k_embed(
    const float* __restrict__ attrs, const float* __restrict__ ae,
    const float* __restrict__ Wemb, float* __restrict__ h,
    float* __restrict__ e0, int N)
{
    int i = blockIdx.x * blockDim.x + threadIdx.x;
    if (i >= N) return;
    float a[10];
#pragma unroll
    for (int k = 0; k < 10; k++) a[k] = attrs[i * 10 + k];
    float e = 0.f;
#pragma unroll
    for (int k = 0; k < 10; k++) e += a[k] * ae[k];
    e0[i] = e;
#pragma unroll
    for (int c = 0; c < 32; c++) {
        float v = 0.f;
#pragma unroll
        for (int k = 0; k < 10; k++) v += a[k] * Wemb[k * 32 + c];
        h[i * 32 + c] = v;
    }
}

// Edge kernel with LDS-staged, channel-parallel coalesced atomics.
// tw = silu(ef@W1)@W2[:, :32];  acc[scatter] += feat[gather] * tw
// swapdir=0: gather=sender, scatter=receiver (forward message passing)
// swapdir=1: gather=receiver, scatter=sender  (backward g1 scatter)
__global__ __launch_bounds__(256) void k_edge_mlp(
    const float* __restrict__ pos, const float* __restrict__ shifts,
    const int* __restrict__ ei, const float* __restrict__ W1,
    const float* __restrict__ W2, const float* __restrict__ feat,
    float* __restrict__ acc, int E, int swapdir)
{
    __shared__ float m_lds[256][33];   // padded: conflict-free both phases
    __shared__ int   dst_lds[256];

    int tid = threadIdx.x;
    int e = blockIdx.x * 256 + tid;
    int dst = -1;

    if (e < E) {
        int s = ei[e], r = ei[E + e];
        float vx = pos[3 * r + 0] - pos[3 * s + 0] + shifts[3 * e + 0];
        float vy = pos[3 * r + 1] - pos[3 * s + 1] + shifts[3 * e + 1];
        float vz = pos[3 * r + 2] - pos[3 * s + 2] + shifts[3 * e + 2];
        float ss2 = vx * vx + vy * vy + vz * vz;
        float L = sqrtf(fmaxf(ss2, 1e-12f));
        float u = L * INV_R;
        if (u < 1.f) {   // else fc=0 -> zero contribution
            float invL = 1.f / L;
            float ef[8];
            radial_ef(u, invL, ef);

            float tw[32];
#pragma unroll
            for (int c = 0; c < 32; c++) tw[c] = 0.f;
            for (int j = 0; j < 64; j++) {
                float s1 = 0.f;
#pragma unroll
                for (int k = 0; k < 8; k++) s1 += ef[k] * W1[k * 64 + j];
                float act = s1 * sigm(s1);
                const float* w2 = W2 + j * 96;
#pragma unroll
                for (int c = 0; c < 32; c++) tw[c] += act * w2[c];
            }

            int gn = swapdir ? r : s;
            dst = swapdir ? s : r;
            const float* fs = feat + (size_t)gn * 32;
#pragma unroll
            for (int c = 0; c < 32; c++) m_lds[tid][c] = fs[c] * tw[c];
        }
    }
    dst_lds[tid] = dst;
    __syncthreads();

    // channel-parallel atomic phase: lane c of each 32-lane group writes
    // channel c of one edge -> 32 contiguous dwords per edge (coalesced)
    int grp = tid >> 5;
    int c   = tid & 31;
#pragma unroll 4
    for (int k = 0; k < 32; k++) {
        int slot = grp * 32 + k;
        int d = dst_lds[slot];
        if (d >= 0)
            unsafeAtomicAdd(&acc[(size_t)d * 32 + c], m_lds[slot][c]);
    }
}

__global__ __launch_bounds__(256) void k_node1(
    const float* __restrict__ h, float* __restrict__ A1,
    const float* __restrict__ Wr1, float* __restrict__ e1, int N)
{
    int i = blockIdx.x * blockDim.x + threadIdx.x;
    if (i >= N) return;
    float dot = 0.f;
#pragma unroll
    for (int c = 0; c < 32; c++) {
        float v = A1[i * 32 + c] * INV_AVG + h[i * 32 + c];
        A1[i * 32 + c] = v;
        dot += v * Wr1[c];
    }
    e1[i] = dot;
}

__global__ __launch_bounds__(256) void k_node2(
    const float* __restrict__ A2acc, const float* __restrict__ A1,
    const float* __restrict__ Wm1, const float* __restrict__ Wm2,
    const float* __restrict__ e0, const float* __restrict__ e1,
    float* __restrict__ g2, float* __restrict__ node_e,
    float* __restrict__ total, const int* __restrict__ batch, int N)
{
    __shared__ float bins[32];
    if (threadIdx.x < 32) bins[threadIdx.x] = 0.f;
    __syncthreads();
    int i = blockIdx.x * blockDim.x + threadIdx.x;
    if (i < N) {
        float A2[32];
#pragma unroll
        for (int c = 0; c < 32; c++)
            A2[c] = A2acc[i * 32 + c] * INV_AVG + A1[i * 32 + c];
        float z[16];
#pragma unroll
        for (int k = 0; k < 16; k++) {
            float v = 0.f;
#pragma unroll
            for (int c = 0; c < 32; c++) v += A2[c] * Wm1[c * 16 + k];
            z[k] = v;
        }
        float e2 = 0.f;
        float wk[16];
#pragma unroll
        for (int k = 0; k < 16; k++) {
            float sg = sigm(z[k]);
            float m2 = Wm2[k];
            e2 += z[k] * sg * m2;
            wk[k] = m2 * sg * (1.f + z[k] * (1.f - sg));  // Wm2 * silu'(z)
        }
#pragma unroll
        for (int c = 0; c < 32; c++) {
            float v = 0.f;
#pragma unroll
            for (int k = 0; k < 16; k++) v += Wm1[c * 16 + k] * wk[k];
            g2[i * 32 + c] = v;
        }
        float ne = e0[i] + e1[i] + e2;
        node_e[i] = ne;
        atomicAdd(&bins[batch[i]], ne);
    }
    __syncthreads();
    if (threadIdx.x < 32) unsafeAtomicAdd(&total[threadIdx.x], bins[threadIdx.x]);
}

__global__ __launch_bounds__(256) void k_node3(
    float* __restrict__ g1, const float* __restrict__ g2,
    const float* __restrict__ Wr1, int N)
{
    int i = blockIdx.x * blockDim.x + threadIdx.x;
    if (i >= N) return;
#pragma unroll
    for (int c = 0; c < 32; c++)
        g1[i * 32 + c] = g1[i * 32 + c] * INV_AVG + g2[i * 32 + c] + Wr1[c];
}

__global__ __launch_bounds__(256) void k_edge_force(
    const float* __restrict__ pos, const float* __restrict__ shifts,
    const int* __restrict__ ei,
    const float* __restrict__ W1a, const float* __restrict__ W2a,
    const float* __restrict__ W1b, const float* __restrict__ W2b,
    const float* __restrict__ h, const float* __restrict__ A1,
    const float* __restrict__ g1, const float* __restrict__ g2,
    float* __restrict__ forces, int E)
{
    int e = blockIdx.x * blockDim.x + threadIdx.x;
    if (e >= E) return;
    int s = ei[e], r = ei[E + e];
    float vx = pos[3 * r + 0] - pos[3 * s + 0] + shifts[3 * e + 0];
    float vy = pos[3 * r + 1] - pos[3 * s + 1] + shifts[3 * e + 1];
    float vz = pos[3 * r + 2] - pos[3 * s + 2] + shifts[3 * e + 2];
    float ss2 = vx * vx + vy * vy + vz * vz;
    if (ss2 <= 1e-12f) return;           // grad of maximum() is 0 -> zero force
    float L = sqrtf(ss2);
    float u = L * INV_R;
    if (u >= 1.f) return;                // d(ef)/dL = 0 beyond cutoff
    float invL = 1.f / L;

    float ef[8], dd[8], def[8];
    radial_ef_d(u, invL, ef, dd);
#pragma unroll
    for (int k = 0; k < 8; k++) def[k] = 0.f;

    // branch a: dtw1 = (1/16) * g1[recv] * h[send]
    {
        float dtw[32];
        const float* gr = g1 + (size_t)r * 32;
        const float* fs = h + (size_t)s * 32;
#pragma unroll
        for (int c = 0; c < 32; c++) dtw[c] = INV_AVG * gr[c] * fs[c];
        for (int j = 0; j < 64; j++) {
            float s1 = 0.f;
#pragma unroll
            for (int k = 0; k < 8; k++) s1 += ef[k] * W1a[k * 64 + j];
            float da = 0.f;
            const float* w2 = W2a + j * 96;
#pragma unroll
            for (int c = 0; c < 32; c++) da += w2[c] * dtw[c];
            float sg = sigm(s1);
            float ds = sg * (1.f + s1 * (1.f - sg)) * da;   // silu'(s1) * da
#pragma unroll
            for (int k = 0; k < 8; k++) def[k] += W1a[k * 64 + j] * ds;
        }
    }
    // branch b: dtw2 = (1/16) * g2[recv] * A1[send]
    {
        float dtw[32];
        const float* gr = g2 + (size_t)r * 32;
        const float* fs = A1 + (size_t)s * 32;
#pragma unroll
        for (int c = 0; c < 32; c++) dtw[c] = INV_AVG * gr[c] * fs[c];
        for (int j = 0; j < 64; j++) {
            float s1 = 0.f;
#pragma unroll
            for (int k = 0; k < 8; k++) s1 += ef[k] * W1b[k * 64 + j];
            float da = 0.f;
            const float* w2 = W2b + j * 96;
#pragma unroll
            for (int c = 0; c < 32; c++) da += w2[c] * dtw[c];
            float sg = sigm(s1);
            float ds = sg * (1.f + s1 * (1.f - sg)) * da;
#pragma unroll
            for (int k = 0; k < 8; k++) def[k] += W1b[k * 64 + j] * ds;
        }
    }

    float dL = 0.f;
#pragma unroll
    for (int k = 0; k < 8; k++) dL += def[k] * dd[k];

    // dE/dpos[r] = dL * vec/L ; forces = -grad
    float sc = -dL * invL;
    float fx = sc * vx, fy = sc * vy, fz = sc * vz;
    unsafeAtomicAdd(&forces[3 * r + 0], fx);
    unsafeAtomicAdd(&forces[3 * r + 1], fy);
    unsafeAtomicAdd(&forces[3 * r + 2], fz);
    unsafeAtomicAdd(&forces[3 * s + 0], -fx);
    unsafeAtomicAdd(&forces[3 * s + 1], -fy);
    unsafeAtomicAdd(&forces[3 * s + 2], -fz);
}

extern "C" void kernel_launch(void* const* d_in, const int* in_sizes, int n_in,
                              void* d_out, int out_size, void* d_ws, size_t ws_size,
                              hipStream_t stream)
{
    const float* pos    = (const float*)d_in[0];
    const float* attrs  = (const float*)d_in[1];
    const float* shifts = (const float*)d_in[2];
    const float* ae     = (const float*)d_in[3];
    const float* Wemb   = (const float*)d_in[4];
    const float* W1a    = (const float*)d_in[5];
    const float* W2a    = (const float*)d_in[6];
    const float* Wr1    = (const float*)d_in[7];
    const float* W1b    = (const float*)d_in[8];
    const float* W2b    = (const float*)d_in[9];
    const float* Wm1    = (const float*)d_in[10];
    const float* Wm2    = (const float*)d_in[11];
    const int*   ei     = (const int*)d_in[12];
    const int*   batch  = (const int*)d_in[13];

    int N = in_sizes[13];
    int E = in_sizes[12] / 2;

    float* out    = (float*)d_out;
    float* total  = out;                 // 32
    float* node_e = out + 32;            // N
    float* forces = out + 32 + N;        // 3N

    float* ws = (float*)d_ws;
    size_t NC = (size_t)N * 32;
    float* h  = ws;            // N*32
    float* A1 = h  + NC;       // N*32 : acc then A1_0 in place
    float* A2 = A1 + NC;       // N*32 : acc
    float* g2 = A2 + NC;       // N*32
    float* g1 = g2 + NC;       // N*32 : acc then final in place
    float* e0 = g1 + NC;       // N
    float* e1 = e0 + N;        // N

    hipMemsetAsync(A1, 0, NC * sizeof(float), stream);
    hipMemsetAsync(A2, 0, NC * sizeof(float), stream);
    hipMemsetAsync(g1, 0, NC * sizeof(float), stream);
    hipMemsetAsync(total, 0, 32 * sizeof(float), stream);
    hipMemsetAsync(forces, 0, (size_t)N * 3 * sizeof(float), stream);

    int nb_n = (N + 255) / 256;
    int nb_e = (E + 255) / 256;

    k_embed<<<nb_n, 256, 0, stream>>>(attrs, ae, Wemb, h, e0, N);
    k_edge_mlp<<<nb_e, 256, 0, stream>>>(pos, shifts, ei, W1a, W2a, h, A1, E, 0);
    k_node1<<<nb_n, 256, 0, stream>>>(h, A1, Wr1, e1, N);
    k_edge_mlp<<<nb_e, 256, 0, stream>>>(pos, shifts, ei, W1b, W2b, A1, A2, E, 0);
    k_node2<<<nb_n, 256, 0, stream>>>(A2, A1, Wm1, Wm2, e0, e1, g2, node_e, total, batch, N);
    k_edge_mlp<<<nb_e, 256, 0, stream>>>(pos, shifts, ei, W1b, W2b, g2, g1, E, 1);
    k_node3<<<nb_n, 256, 0, stream>>>(g1, g2, Wr1, N);
    k_edge_force<<<nb_e, 256, 0, stream>>>(pos, shifts, ei, W1a, W2a, W1b, W2b,
                                           h, A1, g1, g2, forces, E);
}